// Round 25
// baseline (101.014 us; speedup 1.0000x reference)
//
#include <hip/hip_runtime.h>

#define T_SEQ 4096
#define NBATCH 4
#define CDIM 1024
#define NHEAD 64
#define SCALE (1.0f / 32.0f)
#define LOG2E 1.4426950408889634f
#define BT (NBATCH * T_SEQ)
#define NW 8             // waves per attn block (key-split factor)
#define WREG 8960        // per-wave LDS region bytes: o[32][68] f32 + m + l

typedef __bf16 bf16x8 __attribute__((ext_vector_type(8)));
typedef float f32x4 __attribute__((ext_vector_type(4)));
typedef float f32x16 __attribute__((ext_vector_type(16)));

__device__ __forceinline__ unsigned short f2bf(float f) {
  union { float f; unsigned u; } x;
  x.f = f;
  unsigned r = x.u + 0x7FFFu + ((x.u >> 16) & 1u);
  return (unsigned short)(r >> 16);
}

// RNE pack of two f32 into one u32 of 2 bf16 via f2bf (NOT cvt_pk: R24
// showed v_cvt_pk_bf16_f32 rounds differently — applying it to x pushed
// absmax 0.0156 -> 0.107. cvt_pk remains safe ONLY for P in [0,1]).
__device__ __forceinline__ unsigned pack_rne(float lo, float hi) {
  return (unsigned)f2bf(lo) | ((unsigned)f2bf(hi) << 16);
}

// cvt_pk: used exclusively in attn's P-path (verified R10-R23).
__device__ __forceinline__ unsigned cvt_pk(float lo, float hi) {
  unsigned d;
  asm("v_cvt_pk_bf16_f32 %0, %1, %2" : "=v"(d) : "v"(lo), "v"(hi));
  return d;
}

// lane-half swap, VALU pipe. Distinct-value operands only (R15 lesson).
__device__ __forceinline__ void swap32(unsigned& a, unsigned& b) {
  asm("v_permlane32_swap_b32 %0, %1" : "+v"(a), "+v"(b));
}

__device__ __forceinline__ f32x4 mfma16(bf16x8 a, bf16x8 b, f32x4 c) {
  return __builtin_amdgcn_mfma_f32_16x16x32_bf16(a, b, c, 0, 0, 0);
}

__device__ __forceinline__ f32x16 mfma32(bf16x8 a, bf16x8 b, f32x16 c) {
  return __builtin_amdgcn_mfma_f32_32x32x16_bf16(a, b, c, 0, 0, 0);
}

// ---------------------------------------------------------------------------
// Kernel 1: Wt transpose-prep (R19-verified, coalesced both sides).
// ---------------------------------------------------------------------------
__global__ __launch_bounds__(256) void prep_w(
    const float* __restrict__ Wq, const float* __restrict__ Wk,
    const float* __restrict__ Wv, unsigned short* __restrict__ Wt) {
  __shared__ float wlds[64][65];
  const int m = blockIdx.x / 16;
  const int kt = blockIdx.x % 16;
  const float* W = (m == 0) ? Wq : (m == 1) ? Wk : Wv;
  const float s = (m == 0) ? (SCALE * LOG2E) : 1.0f;
  const int tid = threadIdx.x;
  const int la = tid & 63;
  const int gr = tid >> 6;

  for (int i = 0; i < 16; i++) {
    int kl = gr * 16 + i;
    wlds[kl][la] = W[(size_t)(kt * 64 + kl) * NHEAD + la];
  }
  __syncthreads();
  for (int i = 0; i < 16; i++) {
    int cl = gr * 16 + i;
    Wt[(size_t)(m * 64 + cl) * CDIM + kt * 64 + la] = f2bf(wlds[la][cl] * s);
  }
}

// ---------------------------------------------------------------------------
// Kernel 2: fused QKV projection — BARRIER-FREE, LDS-FREE (R24 structure,
// R25 fix: x packed via pack_rne/f2bf, NOT cvt_pk). A-frag loaded directly
// from global x (lane(c15,g) reads 32 contiguous bytes, coalesced); waves
// read x redundantly (4x, L3-resident) in exchange for zero fences — only
// loop-carried dep is acc, so iterations overlap freely (#pragma unroll 2).
// 512 blocks x 4 waves, M32, cols w*48..+47.
// ---------------------------------------------------------------------------
__global__ __launch_bounds__(256) void proj_qkv(
    const float* __restrict__ x, const unsigned short* __restrict__ Wt,
    unsigned short* __restrict__ qws, unsigned short* __restrict__ kws,
    unsigned short* __restrict__ vtws) {
  const int tid = threadIdx.x;
  const int lane = tid & 63;
  const int w = tid >> 6;
  const int g = lane >> 4;
  const int c15 = lane & 15;
  const int rb = blockIdx.x * 32;

  f32x4 acc[2][3];
  for (int i = 0; i < 2; i++)
    for (int j = 0; j < 3; j++) acc[i][j] = (f32x4){0.f, 0.f, 0.f, 0.f};

  const float* xr0 = x + (size_t)(rb + c15) * CDIM + g * 8;
  const float* xr1 = x + (size_t)(rb + 16 + c15) * CDIM + g * 8;
  const unsigned short* wb = Wt + g * 8;

#pragma unroll 2
  for (int k0 = 0; k0 < CDIM; k0 += 128) {
    float4 xf[4][2][2];
    for (int kk = 0; kk < 4; kk++) {
      xf[kk][0][0] = *(const float4*)(xr0 + k0 + kk * 32);
      xf[kk][0][1] = *(const float4*)(xr0 + k0 + kk * 32 + 4);
      xf[kk][1][0] = *(const float4*)(xr1 + k0 + kk * 32);
      xf[kk][1][1] = *(const float4*)(xr1 + k0 + kk * 32 + 4);
    }
    bf16x8 wfrag[4][3];
    for (int kk = 0; kk < 4; kk++)
      for (int bn = 0; bn < 3; bn++) {
        int col = w * 48 + bn * 16 + c15;
        wfrag[kk][bn] = *(const bf16x8*)&wb[(size_t)col * CDIM + k0 + kk * 32];
      }

    for (int kk = 0; kk < 4; kk++) {
      union { unsigned u[4]; bf16x8 v; } a0, a1;
      a0.u[0] = pack_rne(xf[kk][0][0].x, xf[kk][0][0].y);
      a0.u[1] = pack_rne(xf[kk][0][0].z, xf[kk][0][0].w);
      a0.u[2] = pack_rne(xf[kk][0][1].x, xf[kk][0][1].y);
      a0.u[3] = pack_rne(xf[kk][0][1].z, xf[kk][0][1].w);
      a1.u[0] = pack_rne(xf[kk][1][0].x, xf[kk][1][0].y);
      a1.u[1] = pack_rne(xf[kk][1][0].z, xf[kk][1][0].w);
      a1.u[2] = pack_rne(xf[kk][1][1].x, xf[kk][1][1].y);
      a1.u[3] = pack_rne(xf[kk][1][1].z, xf[kk][1][1].w);
      for (int bn = 0; bn < 3; bn++) {
        acc[0][bn] = mfma16(a0.v, wfrag[kk][bn], acc[0][bn]);
        acc[1][bn] = mfma16(a1.v, wfrag[kk][bn], acc[1][bn]);
      }
    }
  }

  for (int mt = 0; mt < 2; mt++)
    for (int bn = 0; bn < 3; bn++) {
      int col = w * 48 + bn * 16 + c15;
      int row0 = rb + mt * 16 + 4 * g;
      for (int r = 0; r < 4; r++) {
        unsigned short v = f2bf(acc[mt][bn][r]);
        int t = row0 + r;
        if (col < 64)
          qws[(size_t)t * 64 + col] = v;
        else if (col < 128)
          kws[(size_t)t * 64 + (col - 64)] = v;
        else
          vtws[(size_t)(col - 128) * BT + t] = v;
      }
    }
}

// ---------------------------------------------------------------------------
// Kernel 3: causal flash attention — BYTE-IDENTICAL to R21 (best measured,
// concurrent light/heavy q-tiles, shared K/V load, two independent softmax
// chains; 32x32 MFMA, shfl_xor(32) max/sum, branchless rescale, cvt_pk +
// distinct-value permlane swaps).
// ---------------------------------------------------------------------------
__global__ __launch_bounds__(512, 2) void attn_fwd(
    const unsigned short* __restrict__ qws, const unsigned short* __restrict__ kws,
    const unsigned short* __restrict__ vtws, float* __restrict__ out) {
  __shared__ __align__(16) char smem[NW * WREG];  // 70 KiB
  const int tid = threadIdx.x;
  const int lane = tid & 63;
  const int w = tid >> 6;
  const int q31 = lane & 31;
  const int hi = lane >> 5;
  const int b = blockIdx.x >> 6;
  const int pi = blockIdx.x & 63;
  const size_t rowbase = (size_t)b * T_SEQ;
  char* wbase = smem + w * WREG;

  const int qb0 = pi * 32;            // light tile
  const int qb1 = (127 - pi) * 32;    // heavy tile
  const int n0 = pi + 1;
  const int n1 = 128 - pi;

  bf16x8 qf0[4], qf1[4];
  for (int h2 = 0; h2 < 4; h2++) {
    qf0[h2] =
        *(const bf16x8*)&qws[(rowbase + qb0 + q31) * 64 + h2 * 16 + hi * 8];
    qf1[h2] =
        *(const bf16x8*)&qws[(rowbase + qb1 + q31) * 64 + h2 * 16 + hi * 8];
  }

  f32x16 o0[2], o1[2];
  o0[0] = (f32x16)0.f; o0[1] = (f32x16)0.f;
  o1[0] = (f32x16)0.f; o1[1] = (f32x16)0.f;
  float m0 = -1e30f, m1 = -1e30f;
  float l0 = 0.f, l1 = 0.f;

  auto STEP = [&](int st, int kt, int qb_, int nst, bf16x8 (&qf_)[4],
                  f32x16 (&o_)[2], float& mrow_, float& lrun_,
                  bf16x8 (&ka)[4], bf16x8 (&va)[2][2]) {
    f32x16 s = (f32x16)0.f;
    for (int h2 = 0; h2 < 4; h2++) s = mfma32(ka[h2], qf_[h2], s);

    float sv[16];
    for (int r = 0; r < 16; r++) sv[r] = s[r];
    if (st == nst - 1) {
      for (int r = 0; r < 16; r++) {
        int key = kt + (r & 3) + 8 * (r >> 2) + 4 * hi;
        if (key > qb_ + q31) sv[r] = -1e30f;
      }
    }

    float t01 = fmaxf(sv[0], sv[1]), t23 = fmaxf(sv[2], sv[3]);
    float t45 = fmaxf(sv[4], sv[5]), t67 = fmaxf(sv[6], sv[7]);
    float t89 = fmaxf(sv[8], sv[9]), tab = fmaxf(sv[10], sv[11]);
    float tcd = fmaxf(sv[12], sv[13]), tef = fmaxf(sv[14], sv[15]);
    float t = fmaxf(fmaxf(fmaxf(t01, t23), fmaxf(t45, t67)),
                    fmaxf(fmaxf(t89, tab), fmaxf(tcd, tef)));
    t = fmaxf(t, __shfl_xor(t, 32));

    float mn = fmaxf(mrow_, t);
    float a = exp2f(mrow_ - mn);
    mrow_ = mn;
    o_[0] *= a;
    o_[1] *= a;
    lrun_ *= a;

    float p[16];
    for (int r = 0; r < 16; r++) p[r] = exp2f(sv[r] - mrow_);

    float ssum = 0.f;
    for (int r = 0; r < 16; r++) ssum += p[r];
    lrun_ += ssum + __shfl_xor(ssum, 32);

    unsigned X[8];
    for (int jj = 0; jj < 8; jj++) X[jj] = cvt_pk(p[2 * jj], p[2 * jj + 1]);
    swap32(X[0], X[2]);
    swap32(X[1], X[3]);
    swap32(X[4], X[6]);
    swap32(X[5], X[7]);

    union { unsigned u[4]; bf16x8 v; } bf0, bf1;
    bf0.u[0] = X[0]; bf0.u[1] = X[1]; bf0.u[2] = X[2]; bf0.u[3] = X[3];
    bf1.u[0] = X[4]; bf1.u[1] = X[5]; bf1.u[2] = X[6]; bf1.u[3] = X[7];

    for (int nt = 0; nt < 2; nt++) {
      o_[nt] = mfma32(va[nt][0], bf0.v, o_[nt]);
      o_[nt] = mfma32(va[nt][1], bf1.v, o_[nt]);
    }
  };

  for (int st = w; st < n1; st += NW) {
    const int kt = st * 32;
    bf16x8 ka[4];
    for (int h2 = 0; h2 < 4; h2++)
      ka[h2] = *(const bf16x8*)&kws[(rowbase + kt + q31) * 64 + h2 * 16 + hi * 8];
    bf16x8 va[2][2];
    for (int nt = 0; nt < 2; nt++)
      for (int ki = 0; ki < 2; ki++)
        va[nt][ki] = *(const bf16x8*)&vtws[(size_t)(nt * 32 + q31) * BT +
                                           rowbase + kt + ki * 16 + hi * 8];

    STEP(st, kt, qb1, n1, qf1, o1, m1, l1, ka, va);
    if (st < n0)
      STEP(st, kt, qb0, n0, qf0, o0, m0, l0, ka, va);
  }

  auto EPI = [&](int qb_, f32x16 (&o_)[2], float mrow_, float lrun_) {
    float* ow = (float*)wbase;
    float* mw = (float*)(wbase + 8704);
    float* lw = (float*)(wbase + 8832);
    for (int nt = 0; nt < 2; nt++)
      for (int r = 0; r < 16; r++) {
        int d = nt * 32 + (r & 3) + 8 * (r >> 2) + 4 * hi;
        ow[q31 * 68 + d] = o_[nt][r];
      }
    if (hi == 0) {
      mw[q31] = mrow_;
      lw[q31] = lrun_;
    }
    __syncthreads();

    for (int i = 0; i < 4; i++) {
      int e = tid + i * 512;
      int row = e >> 6;
      int d = e & 63;
      float M = -1e30f;
      for (int ww = 0; ww < NW; ww++)
        M = fmaxf(M, ((const float*)(smem + ww * WREG + 8704))[row]);
      float L = 0.f, O = 0.f;
      for (int ww = 0; ww < NW; ww++) {
        float mv = ((const float*)(smem + ww * WREG + 8704))[row];
        float f = exp2f(mv - M);
        L += f * ((const float*)(smem + ww * WREG + 8832))[row];
        O += f * ((const float*)(smem + ww * WREG))[row * 68 + d];
      }
      out[(rowbase + qb_ + row) * 64 + d] = O / L;
    }
    __syncthreads();
  };
  EPI(qb1, o1, m1, l1);
  EPI(qb0, o0, m0, l0);
}

// ---------------------------------------------------------------------------
extern "C" void kernel_launch(void* const* d_in, const int* in_sizes, int n_in,
                              void* d_out, int out_size, void* d_ws, size_t ws_size,
                              hipStream_t stream) {
  const float* x = (const float*)d_in[0];
  const float* Wq = (const float*)d_in[1];
  const float* Wk = (const float*)d_in[2];
  const float* Wv = (const float*)d_in[3];
  float* out = (float*)d_out;

  char* ws = (char*)d_ws;
  unsigned short* Wt = (unsigned short*)(ws);                          // 384 KB
  unsigned short* qws = (unsigned short*)(ws + 393216);                // 2 MB
  unsigned short* kws = (unsigned short*)(ws + 393216 + 2097152);      // 2 MB
  unsigned short* vtws = (unsigned short*)(ws + 393216 + 2 * 2097152); // 2 MB

  prep_w<<<dim3(48), dim3(256), 0, stream>>>(Wq, Wk, Wv, Wt);
  proj_qkv<<<dim3(512), dim3(256), 0, stream>>>(x, Wt, qws, kws, vtws);
  attn_fwd<<<dim3(256), dim3(512), 0, stream>>>(qws, kws, vtws, out);
}

// Round 26
// 78.926 us; speedup vs baseline: 1.2799x; 1.2799x over previous
//
#include <hip/hip_runtime.h>

#define T_SEQ 4096
#define NBATCH 4
#define CDIM 1024
#define NHEAD 64
#define SCALE (1.0f / 32.0f)
#define LOG2E 1.4426950408889634f
#define BT (NBATCH * T_SEQ)
#define NW 8             // waves per attn block (key-split factor)
#define WREG 8960        // per-wave LDS region bytes: o[32][68] f32 + m + l

typedef __bf16 bf16x8 __attribute__((ext_vector_type(8)));
typedef float f32x4 __attribute__((ext_vector_type(4)));
typedef float f32x16 __attribute__((ext_vector_type(16)));

__device__ __forceinline__ unsigned short f2bf(float f) {
  union { float f; unsigned u; } x;
  x.f = f;
  unsigned r = x.u + 0x7FFFu + ((x.u >> 16) & 1u);
  return (unsigned short)(r >> 16);
}

// cvt_pk: used exclusively in attn's P-path (P in [0,1]; verified R10-R23).
// NOT for x/general values — rounds differently from RNE (R24: absmax 7x).
__device__ __forceinline__ unsigned cvt_pk(float lo, float hi) {
  unsigned d;
  asm("v_cvt_pk_bf16_f32 %0, %1, %2" : "=v"(d) : "v"(lo), "v"(hi));
  return d;
}

// lane-half swap, VALU pipe. Distinct-value operands only (R15 lesson).
__device__ __forceinline__ void swap32(unsigned& a, unsigned& b) {
  asm("v_permlane32_swap_b32 %0, %1" : "+v"(a), "+v"(b));
}

__device__ __forceinline__ f32x4 mfma16(bf16x8 a, bf16x8 b, f32x4 c) {
  return __builtin_amdgcn_mfma_f32_16x16x32_bf16(a, b, c, 0, 0, 0);
}

__device__ __forceinline__ f32x16 mfma32(bf16x8 a, bf16x8 b, f32x16 c) {
  return __builtin_amdgcn_mfma_f32_32x32x16_bf16(a, b, c, 0, 0, 0);
}

// ---------------------------------------------------------------------------
// Kernel 1: Wt transpose-prep (R19-verified, coalesced both sides).
// ---------------------------------------------------------------------------
__global__ __launch_bounds__(256) void prep_w(
    const float* __restrict__ Wq, const float* __restrict__ Wk,
    const float* __restrict__ Wv, unsigned short* __restrict__ Wt) {
  __shared__ float wlds[64][65];
  const int m = blockIdx.x / 16;
  const int kt = blockIdx.x % 16;
  const float* W = (m == 0) ? Wq : (m == 1) ? Wk : Wv;
  const float s = (m == 0) ? (SCALE * LOG2E) : 1.0f;
  const int tid = threadIdx.x;
  const int la = tid & 63;
  const int gr = tid >> 6;

  for (int i = 0; i < 16; i++) {
    int kl = gr * 16 + i;
    wlds[kl][la] = W[(size_t)(kt * 64 + kl) * NHEAD + la];
  }
  __syncthreads();
  for (int i = 0; i < 16; i++) {
    int cl = gr * 16 + i;
    Wt[(size_t)(m * 64 + cl) * CDIM + kt * 64 + la] = f2bf(wlds[la][cl] * s);
  }
}

// ---------------------------------------------------------------------------
// Kernel 2: fused QKV projection — R16/R21 form (session-best, 41us floor).
// M-tile 32, 512 blocks x 4 waves, LDS double-buffer (one barrier/iter),
// hoisted Wt loads. FINAL after 7 restructures (barrier-free, BK256, M16,
// sched_barrier, 1-wave stream) all landed 41-70us: hipcc's VGPR
// minimization serializes any lower-work variant; the 41us floor is a
// per-iteration latency floor (all pipes <12%), not a pipe bound.
// ---------------------------------------------------------------------------
__global__ __launch_bounds__(256) void proj_qkv(
    const float* __restrict__ x, const unsigned short* __restrict__ Wt,
    unsigned short* __restrict__ qws, unsigned short* __restrict__ kws,
    unsigned short* __restrict__ vtws) {
  __shared__ unsigned short xlds[2][32][136];
  const int tid = threadIdx.x;
  const int lane = tid & 63;
  const int w = tid >> 6;
  const int g = lane >> 4;
  const int c15 = lane & 15;
  const int rb = blockIdx.x * 32;

  f32x4 acc[2][3];
  for (int i = 0; i < 2; i++)
    for (int j = 0; j < 3; j++) acc[i][j] = (f32x4){0.f, 0.f, 0.f, 0.f};

  const int sr = tid >> 3;
  const int scc = (tid & 7) * 16;
  const float* xrow = x + (size_t)(rb + sr) * CDIM + scc;

  {
    float4 cur[4];
    for (int i = 0; i < 4; i++) cur[i] = *(const float4*)(xrow + i * 4);
    unsigned short pk[16];
    for (int i = 0; i < 4; i++) {
      pk[i * 4 + 0] = f2bf(cur[i].x);
      pk[i * 4 + 1] = f2bf(cur[i].y);
      pk[i * 4 + 2] = f2bf(cur[i].z);
      pk[i * 4 + 3] = f2bf(cur[i].w);
    }
    *(bf16x8*)&xlds[0][sr][scc] = *(bf16x8*)&pk[0];
    *(bf16x8*)&xlds[0][sr][scc + 8] = *(bf16x8*)&pk[8];
  }
  __syncthreads();

  int pb = 0;
  for (int k0 = 0; k0 < CDIM; k0 += 128) {
    const bool more = (k0 + 128 < CDIM);
    float4 nxt[4];
    if (more)
      for (int i = 0; i < 4; i++)
        nxt[i] = *(const float4*)(xrow + k0 + 128 + i * 4);

    bf16x8 wfrag[4][3];
    for (int kk = 0; kk < 4; kk++)
      for (int bn = 0; bn < 3; bn++) {
        int col = w * 48 + bn * 16 + c15;
        wfrag[kk][bn] =
            *(const bf16x8*)&Wt[(size_t)col * CDIM + k0 + kk * 32 + g * 8];
      }

    for (int kk = 0; kk < 4; kk++) {
      bf16x8 a[2];
      for (int mt = 0; mt < 2; mt++)
        a[mt] = *(bf16x8*)&xlds[pb][mt * 16 + c15][kk * 32 + g * 8];
      for (int bn = 0; bn < 3; bn++)
        for (int mt = 0; mt < 2; mt++)
          acc[mt][bn] = mfma16(a[mt], wfrag[kk][bn], acc[mt][bn]);
    }

    if (more) {
      unsigned short pk[16];
      for (int i = 0; i < 4; i++) {
        pk[i * 4 + 0] = f2bf(nxt[i].x);
        pk[i * 4 + 1] = f2bf(nxt[i].y);
        pk[i * 4 + 2] = f2bf(nxt[i].z);
        pk[i * 4 + 3] = f2bf(nxt[i].w);
      }
      *(bf16x8*)&xlds[pb ^ 1][sr][scc] = *(bf16x8*)&pk[0];
      *(bf16x8*)&xlds[pb ^ 1][sr][scc + 8] = *(bf16x8*)&pk[8];
    }
    __syncthreads();
    pb ^= 1;
  }

  for (int mt = 0; mt < 2; mt++)
    for (int bn = 0; bn < 3; bn++) {
      int col = w * 48 + bn * 16 + c15;
      int row0 = rb + mt * 16 + 4 * g;
      for (int r = 0; r < 4; r++) {
        unsigned short v = f2bf(acc[mt][bn][r]);
        int t = row0 + r;
        if (col < 64)
          qws[(size_t)t * 64 + col] = v;
        else if (col < 128)
          kws[(size_t)t * 64 + (col - 64)] = v;
        else
          vtws[(size_t)(col - 128) * BT + t] = v;
      }
    }
}

// ---------------------------------------------------------------------------
// Kernel 3: causal flash attention — R21 (session-best, ~36us).
// 256 blocks x 8 waves, (512,2); each wave runs BOTH its q-tiles (light
// qt=pi, heavy qt=127-pi) concurrently off a SHARED K/V load: two
// independent softmax chains per step (ILP), ~25% fewer K/V loads.
// 32x32 MFMA lane-resident rows; shfl_xor(32) max/sum; branchless rescale;
// cvt_pk + 4 distinct-value permlane swaps -> PV B-frags in-register.
// No LDS/fences in the loop; WREG used by the two sequential epilogues.
// ---------------------------------------------------------------------------
__global__ __launch_bounds__(512, 2) void attn_fwd(
    const unsigned short* __restrict__ qws, const unsigned short* __restrict__ kws,
    const unsigned short* __restrict__ vtws, float* __restrict__ out) {
  __shared__ __align__(16) char smem[NW * WREG];  // 70 KiB
  const int tid = threadIdx.x;
  const int lane = tid & 63;
  const int w = tid >> 6;
  const int q31 = lane & 31;
  const int hi = lane >> 5;
  const int b = blockIdx.x >> 6;
  const int pi = blockIdx.x & 63;
  const size_t rowbase = (size_t)b * T_SEQ;
  char* wbase = smem + w * WREG;

  const int qb0 = pi * 32;            // light tile
  const int qb1 = (127 - pi) * 32;    // heavy tile
  const int n0 = pi + 1;
  const int n1 = 128 - pi;

  bf16x8 qf0[4], qf1[4];
  for (int h2 = 0; h2 < 4; h2++) {
    qf0[h2] =
        *(const bf16x8*)&qws[(rowbase + qb0 + q31) * 64 + h2 * 16 + hi * 8];
    qf1[h2] =
        *(const bf16x8*)&qws[(rowbase + qb1 + q31) * 64 + h2 * 16 + hi * 8];
  }

  f32x16 o0[2], o1[2];
  o0[0] = (f32x16)0.f; o0[1] = (f32x16)0.f;
  o1[0] = (f32x16)0.f; o1[1] = (f32x16)0.f;
  float m0 = -1e30f, m1 = -1e30f;
  float l0 = 0.f, l1 = 0.f;

  auto STEP = [&](int st, int kt, int qb_, int nst, bf16x8 (&qf_)[4],
                  f32x16 (&o_)[2], float& mrow_, float& lrun_,
                  bf16x8 (&ka)[4], bf16x8 (&va)[2][2]) {
    f32x16 s = (f32x16)0.f;
    for (int h2 = 0; h2 < 4; h2++) s = mfma32(ka[h2], qf_[h2], s);

    float sv[16];
    for (int r = 0; r < 16; r++) sv[r] = s[r];
    if (st == nst - 1) {
      for (int r = 0; r < 16; r++) {
        int key = kt + (r & 3) + 8 * (r >> 2) + 4 * hi;
        if (key > qb_ + q31) sv[r] = -1e30f;
      }
    }

    float t01 = fmaxf(sv[0], sv[1]), t23 = fmaxf(sv[2], sv[3]);
    float t45 = fmaxf(sv[4], sv[5]), t67 = fmaxf(sv[6], sv[7]);
    float t89 = fmaxf(sv[8], sv[9]), tab = fmaxf(sv[10], sv[11]);
    float tcd = fmaxf(sv[12], sv[13]), tef = fmaxf(sv[14], sv[15]);
    float t = fmaxf(fmaxf(fmaxf(t01, t23), fmaxf(t45, t67)),
                    fmaxf(fmaxf(t89, tab), fmaxf(tcd, tef)));
    t = fmaxf(t, __shfl_xor(t, 32));

    float mn = fmaxf(mrow_, t);
    float a = exp2f(mrow_ - mn);
    mrow_ = mn;
    o_[0] *= a;
    o_[1] *= a;
    lrun_ *= a;

    float p[16];
    for (int r = 0; r < 16; r++) p[r] = exp2f(sv[r] - mrow_);

    float ssum = 0.f;
    for (int r = 0; r < 16; r++) ssum += p[r];
    lrun_ += ssum + __shfl_xor(ssum, 32);

    unsigned X[8];
    for (int jj = 0; jj < 8; jj++) X[jj] = cvt_pk(p[2 * jj], p[2 * jj + 1]);
    swap32(X[0], X[2]);
    swap32(X[1], X[3]);
    swap32(X[4], X[6]);
    swap32(X[5], X[7]);

    union { unsigned u[4]; bf16x8 v; } bf0, bf1;
    bf0.u[0] = X[0]; bf0.u[1] = X[1]; bf0.u[2] = X[2]; bf0.u[3] = X[3];
    bf1.u[0] = X[4]; bf1.u[1] = X[5]; bf1.u[2] = X[6]; bf1.u[3] = X[7];

    for (int nt = 0; nt < 2; nt++) {
      o_[nt] = mfma32(va[nt][0], bf0.v, o_[nt]);
      o_[nt] = mfma32(va[nt][1], bf1.v, o_[nt]);
    }
  };

  for (int st = w; st < n1; st += NW) {
    const int kt = st * 32;
    bf16x8 ka[4];
    for (int h2 = 0; h2 < 4; h2++)
      ka[h2] = *(const bf16x8*)&kws[(rowbase + kt + q31) * 64 + h2 * 16 + hi * 8];
    bf16x8 va[2][2];
    for (int nt = 0; nt < 2; nt++)
      for (int ki = 0; ki < 2; ki++)
        va[nt][ki] = *(const bf16x8*)&vtws[(size_t)(nt * 32 + q31) * BT +
                                           rowbase + kt + ki * 16 + hi * 8];

    STEP(st, kt, qb1, n1, qf1, o1, m1, l1, ka, va);
    if (st < n0)
      STEP(st, kt, qb0, n0, qf0, o0, m0, l0, ka, va);
  }

  auto EPI = [&](int qb_, f32x16 (&o_)[2], float mrow_, float lrun_) {
    float* ow = (float*)wbase;
    float* mw = (float*)(wbase + 8704);
    float* lw = (float*)(wbase + 8832);
    for (int nt = 0; nt < 2; nt++)
      for (int r = 0; r < 16; r++) {
        int d = nt * 32 + (r & 3) + 8 * (r >> 2) + 4 * hi;
        ow[q31 * 68 + d] = o_[nt][r];
      }
    if (hi == 0) {
      mw[q31] = mrow_;
      lw[q31] = lrun_;
    }
    __syncthreads();

    for (int i = 0; i < 4; i++) {
      int e = tid + i * 512;
      int row = e >> 6;
      int d = e & 63;
      float M = -1e30f;
      for (int ww = 0; ww < NW; ww++)
        M = fmaxf(M, ((const float*)(smem + ww * WREG + 8704))[row]);
      float L = 0.f, O = 0.f;
      for (int ww = 0; ww < NW; ww++) {
        float mv = ((const float*)(smem + ww * WREG + 8704))[row];
        float f = exp2f(mv - M);
        L += f * ((const float*)(smem + ww * WREG + 8832))[row];
        O += f * ((const float*)(smem + ww * WREG))[row * 68 + d];
      }
      out[(rowbase + qb_ + row) * 64 + d] = O / L;
    }
    __syncthreads();
  };
  EPI(qb1, o1, m1, l1);
  EPI(qb0, o0, m0, l0);
}

// ---------------------------------------------------------------------------
extern "C" void kernel_launch(void* const* d_in, const int* in_sizes, int n_in,
                              void* d_out, int out_size, void* d_ws, size_t ws_size,
                              hipStream_t stream) {
  const float* x = (const float*)d_in[0];
  const float* Wq = (const float*)d_in[1];
  const float* Wk = (const float*)d_in[2];
  const float* Wv = (const float*)d_in[3];
  float* out = (float*)d_out;

  char* ws = (char*)d_ws;
  unsigned short* Wt = (unsigned short*)(ws);                          // 384 KB
  unsigned short* qws = (unsigned short*)(ws + 393216);                // 2 MB
  unsigned short* kws = (unsigned short*)(ws + 393216 + 2097152);      // 2 MB
  unsigned short* vtws = (unsigned short*)(ws + 393216 + 2 * 2097152); // 2 MB

  prep_w<<<dim3(48), dim3(256), 0, stream>>>(Wq, Wk, Wv, Wt);
  proj_qkv<<<dim3(512), dim3(256), 0, stream>>>(x, Wt, qws, kws, vtws);
  attn_fwd<<<dim3(256), dim3(512), 0, stream>>>(qws, kws, vtws, out);
}